// Round 7
// baseline (638.996 us; speedup 1.0000x reference)
//
#include <hip/hip_runtime.h>

// Problem constants
#define S_TOK 4096
#define D_DIM 4096
#define O_DIM 4096
#define R_DIM 256
#define E_EXP 8
#define NTOK  8192   // B*S
#define KSPLIT 4

typedef __bf16 bf16x8 __attribute__((ext_vector_type(8)));
typedef float  f32x4  __attribute__((ext_vector_type(4)));

__device__ __forceinline__ unsigned short f2bf(float f) {
  unsigned int u = __float_as_uint(f);
  u += 0x7FFFu + ((u >> 16) & 1u);   // RNE (no NaN in data)
  return (unsigned short)(u >> 16);
}

__device__ __forceinline__ void gload_lds16(const unsigned short* g, unsigned short* l) {
  __builtin_amdgcn_global_load_lds((const __attribute__((address_space(1))) void*)g,
                                   (__attribute__((address_space(3))) void*)l, 16, 0, 0);
}

// Fused counted-wait + barrier as ONE volatile asm with memory clobber.
#define PIPE_FENCE(N)                                                        \
  do {                                                                       \
    asm volatile("s_waitcnt vmcnt(" #N ")\n\ts_barrier" ::: "memory");       \
    __builtin_amdgcn_sched_barrier(0);                                       \
  } while (0)

// ---------------- cast f32 -> bf16, 8 elems/thread ----------------
__global__ void cast8(const float* __restrict__ in, unsigned short* __restrict__ out) {
  size_t g = (size_t)blockIdx.x * 256 + threadIdx.x;
  const float4* i4 = (const float4*)in;
  float4 a = i4[g * 2], b = i4[g * 2 + 1];
  union { unsigned short h[8]; int4 v; } u;
  u.h[0] = f2bf(a.x); u.h[1] = f2bf(a.y); u.h[2] = f2bf(a.z); u.h[3] = f2bf(a.w);
  u.h[4] = f2bf(b.x); u.h[5] = f2bf(b.y); u.h[6] = f2bf(b.z); u.h[7] = f2bf(b.w);
  ((int4*)out)[g] = u.v;
}

// ------------- transpose+cast: in[e][P][Q] f32 -> out[e][Q][P] bf16 -------------
__global__ void transpose_cast(const float* __restrict__ in, unsigned short* __restrict__ out,
                               int P, int Q) {
  __shared__ unsigned short tile[32][33];
  int e = blockIdx.z;
  int pt = blockIdx.x * 32, qt = blockIdx.y * 32;
  const float* ie = in + (size_t)e * P * Q;
  unsigned short* oe = out + (size_t)e * P * Q;
  int tx = threadIdx.x & 31, ty = threadIdx.x >> 5;
  #pragma unroll
  for (int i = 0; i < 32; i += 8) {
    int p = pt + ty + i, q = qt + tx;
    tile[ty + i][tx] = f2bf(ie[(size_t)p * Q + q]);
  }
  __syncthreads();
  #pragma unroll
  for (int i = 0; i < 32; i += 8) {
    int q = qt + ty + i, p = pt + tx;
    oe[(size_t)q * P + p] = tile[tx][ty + i];
  }
}

// ------------- deterministic stable counting sort of tokens by expert -------------
__global__ void sort_tokens(const int* __restrict__ tt, int* __restrict__ token_perm,
                            int* __restrict__ tile_e, int* __restrict__ tile_j0,
                            int* __restrict__ tile_jend, int* __restrict__ ntiles_out) {
  __shared__ int ltt[S_TOK];
  __shared__ int lc[256 * 8];
  __shared__ int basee[8], cnte[8];
  __shared__ int ssl[S_TOK];
  int t = threadIdx.x;
  for (int s = t; s < S_TOK; s += 256) ltt[s] = tt[s];
  __syncthreads();
  int c[8] = {0,0,0,0,0,0,0,0};
  #pragma unroll
  for (int i = 0; i < 16; i++) { int e = ltt[t * 16 + i]; c[e]++; }
  #pragma unroll
  for (int e = 0; e < 8; e++) lc[t * 8 + e] = c[e];
  __syncthreads();
  if (t < 8) {
    int run = 0;
    for (int q = 0; q < 256; q++) { int tmp = lc[q * 8 + t]; lc[q * 8 + t] = run; run += tmp; }
    cnte[t] = run;
  }
  __syncthreads();
  if (t == 0) { int tot = 0; for (int e = 0; e < 8; e++) { basee[e] = tot; tot += cnte[e]; } }
  __syncthreads();
  int off[8];
  #pragma unroll
  for (int e = 0; e < 8; e++) off[e] = basee[e] + lc[t * 8 + e];
  #pragma unroll
  for (int i = 0; i < 16; i++) { int s = t * 16 + i; int e = ltt[s]; ssl[off[e]++] = s; }
  __syncthreads();
  for (int j = t; j < NTOK; j += 256) token_perm[j] = ((j & 1) << 12) + ssl[j >> 1];
  if (t == 0) {
    int nt = 0;
    for (int e = 0; e < 8; e++) {
      int js = 2 * basee[e], je = js + 2 * cnte[e];
      for (int j0 = js; j0 < je; j0 += 128) {
        tile_e[nt] = e; tile_j0[nt] = j0;
        tile_jend[nt] = (je < j0 + 128) ? je : (j0 + 128);
        nt++;
      }
    }
    *ntiles_out = nt;
  }
}

// ===================== 256x256 wave-drift pipelined dense GEMM =====================
// C[8192][4096] = A @ B^T, bf16 in, f32 out. 8 waves (2Mx4N), wave tile 128x64.
// BK=32, NKT=128 K-tiles (R6 BUG: had 64 tiles -> only K=2048 summed).
// 4-ring LDS (4 x {A,B} x 16KB = 128 KiB), stage 3 tiles ahead.
// ONE fused vmcnt+barrier per K-tile; no intra-tile barriers. Within a tile:
// B+A-mh0 reads -> MFMA mh0 (A-mh1 reads in flight underneath) -> MFMA mh1.
// vmcnt ledger (4 loads/stage/thread): steady fence vmcnt(8) => stage(t+1)
// landed, stages t+2,t+3 in flight. Tail: 8...,4,0 descending drain.
__global__ __launch_bounds__(512, 2) void gemm256_dense(
    const unsigned short* __restrict__ A, const unsigned short* __restrict__ B,
    float* __restrict__ C) {
  constexpr int NKT = 128;   // 4096 / 32
  __shared__ __align__(16) unsigned short ldsA[4][8192];  // ring: 256 rows x 32 elems
  __shared__ __align__(16) unsigned short ldsB[4][8192];
  int wg = blockIdx.x;
  wg = (wg & 7) * 64 + (wg >> 3);          // XCD swizzle (512 % 8 == 0, bijective)
  const int bm = wg & 31, bn = wg >> 5;    // 32 x 16 tiles
  const int tid = threadIdx.x, l = tid & 63, w = tid >> 6;
  const int wm = w >> 2, wn = w & 3;       // 2M x 4N wave grid

  // staging source pointers (inverse-swizzled global, linear LDS dest)
  const unsigned short *srcA0, *srcA1, *srcB0, *srcB1;
  {
    int idx0 = tid, row0 = idx0 >> 2;
    int cb0 = ((idx0 & 3) * 16) ^ (((row0 >> 1) & 3) << 4);
    srcA0 = A + (size_t)(bm * 256 + row0) * 4096 + (cb0 >> 1);
    srcB0 = B + (size_t)(bn * 256 + row0) * 4096 + (cb0 >> 1);
    int idx1 = 512 + tid, row1 = idx1 >> 2;
    int cb1 = ((idx1 & 3) * 16) ^ (((row1 >> 1) & 3) << 4);
    srcA1 = A + (size_t)(bm * 256 + row1) * 4096 + (cb1 >> 1);
    srcB1 = B + (size_t)(bn * 256 + row1) * 4096 + (cb1 >> 1);
  }
  const int d0 = tid * 8;  // LDS dest (ushorts); second chunk at +4096

  // swizzled ds_read byte-offsets within one 16KB ring slot
  const int lane15 = l & 15, kb16 = (l >> 4) * 16;
  int offA[8], offB[4];
  #pragma unroll
  for (int m = 0; m < 8; m++) {
    int r = wm * 128 + m * 16 + lane15;
    offA[m] = r * 64 + (kb16 ^ (((r >> 1) & 3) << 4));
  }
  #pragma unroll
  for (int n = 0; n < 4; n++) {
    int r = wn * 64 + n * 16 + lane15;
    offB[n] = r * 64 + (kb16 ^ (((r >> 1) & 3) << 4));
  }

  f32x4 acc[8][4];
  #pragma unroll
  for (int m = 0; m < 8; m++)
    #pragma unroll
    for (int n = 0; n < 4; n++) acc[m][n] = (f32x4){0.f, 0.f, 0.f, 0.f};

  auto stage = [&](int tt) {
    const int ring = tt & 3;
    const int go = tt * 32;
    gload_lds16(srcA0 + go, &ldsA[ring][d0]);
    gload_lds16(srcA1 + go, &ldsA[ring][d0 + 4096]);
    gload_lds16(srcB0 + go, &ldsB[ring][d0]);
    gload_lds16(srcB1 + go, &ldsB[ring][d0 + 4096]);
  };

  auto body = [&](int ring) {
    const char* bA = (const char*)&ldsA[ring][0];
    const char* bB = (const char*)&ldsB[ring][0];
    bf16x8 bfr[4], af0[4], af1[4];
    #pragma unroll
    for (int n = 0; n < 4; n++) bfr[n] = *(const bf16x8*)(bB + offB[n]);
    #pragma unroll
    for (int m = 0; m < 4; m++) af0[m] = *(const bf16x8*)(bA + offA[m]);
    #pragma unroll
    for (int m = 0; m < 4; m++) af1[m] = *(const bf16x8*)(bA + offA[m + 4]);
    // MFMA mh0: compiler waits counted lgkmcnt -> af1 reads still in flight
    __builtin_amdgcn_s_setprio(1);
    #pragma unroll
    for (int m = 0; m < 4; m++)
      #pragma unroll
      for (int n = 0; n < 4; n++)
        acc[m][n] = __builtin_amdgcn_mfma_f32_16x16x32_bf16(af0[m], bfr[n], acc[m][n], 0, 0, 0);
    __builtin_amdgcn_s_setprio(0);
    __builtin_amdgcn_s_setprio(1);
    #pragma unroll
    for (int m = 0; m < 4; m++)
      #pragma unroll
      for (int n = 0; n < 4; n++)
        acc[m + 4][n] = __builtin_amdgcn_mfma_f32_16x16x32_bf16(af1[m], bfr[n], acc[m + 4][n], 0, 0, 0);
    __builtin_amdgcn_s_setprio(0);
  };

  // prologue: stages 0,1,2 (12 loads); vmcnt(8) => stage(0) landed
  stage(0); stage(1); stage(2);
  PIPE_FENCE(8);

  // main: tiles 0..NKT-4, staging t+3 (last stage: t=124 -> tile 127)
  #pragma unroll 1
  for (int t = 0; t < NKT - 3; ++t) {
    stage(t + 3);
    body(t & 3);
    PIPE_FENCE(8);           // stage(t+1) landed; t+2, t+3 in flight
  }
  // tail: descending drain
  body((NKT - 3) & 3);
  PIPE_FENCE(4);             // stage(NKT-2) landed
  body((NKT - 2) & 3);
  PIPE_FENCE(0);             // stage(NKT-1) landed
  body((NKT - 1) & 3);

  const int rowbase = bm * 256 + wm * 128;
  const int colbase = bn * 256 + wn * 64;
  #pragma unroll
  for (int m = 0; m < 8; m++)
    #pragma unroll
    for (int n = 0; n < 4; n++)
      #pragma unroll
      for (int v = 0; v < 4; v++) {
        int r = rowbase + m * 16 + (l >> 4) * 4 + v;
        int cc = colbase + n * 16 + lane15;
        C[(size_t)r * O_DIM + cc] = acc[m][n][v];
      }
}

// ------------- 128x128 skeleton for the LoRA GEMMs -------------
// MODE 1: Hp[kc][j][r] = partial( X[perm[j]] @ A16t[e]^T ) over K-chunk kc (f32 out)
// MODE 2: out_f32[perm[j]] += 2 * H16s @ B16t[e]^T   (scatter-RMW, predicated)
template<int MODE>
__global__ __launch_bounds__(256, 2) void gemm_nt(
    const unsigned short* __restrict__ Aop, const unsigned short* __restrict__ Bop,
    float* __restrict__ outF,
    const int* __restrict__ perm, const int* __restrict__ tile_e,
    const int* __restrict__ tile_j0, const int* __restrict__ tile_jend,
    const int* __restrict__ ntiles, int K) {
  int bm = blockIdx.x, bn = blockIdx.y;
  if (bm >= *ntiles) return;
  int e = tile_e[bm], j0 = tile_j0[bm], jend = tile_jend[bm];
  const int kc = (MODE == 1) ? blockIdx.z : 0;
  const int t = threadIdx.x;
  const int l = t & 63, w = t >> 6;
  __shared__ __align__(16) unsigned short lA[128 * 32];
  __shared__ __align__(16) unsigned short lB[128 * 32];

  const unsigned short* srcA[2];
  const unsigned short* srcB[2];
  #pragma unroll
  for (int ck = 0; ck < 2; ck++) {
    int idx = t + ck * 256;
    int lrow = idx >> 2, lk = (idx & 3) * 8;
    int j = j0 + lrow; if (j > jend - 1) j = jend - 1;
    int grow = (MODE == 1) ? perm[j] : j;
    srcA[ck] = Aop + (size_t)grow * K + lk + kc * 1024;
    int bcol = bn * 128 + lrow;
    const unsigned short* bp = Bop;
    if (MODE == 1) bp += (size_t)e * R_DIM * D_DIM;
    if (MODE == 2) bp += (size_t)e * O_DIM * R_DIM;
    srcB[ck] = bp + (size_t)bcol * K + lk + kc * 1024;
  }

  f32x4 acc[4][4];
  #pragma unroll
  for (int m = 0; m < 4; m++)
    #pragma unroll
    for (int n = 0; n < 4; n++) acc[m][n] = (f32x4){0.f, 0.f, 0.f, 0.f};

  const int wr = w >> 1, wc = w & 1;
  const int ra = wr * 64 + (l & 15);
  const int rb = wc * 64 + (l & 15);
  const int ko = (l >> 4) * 8;

  const int nk = (MODE == 1) ? (1024 / 32) : (K / 32);
  for (int kt = 0; kt < nk; kt++) {
    __syncthreads();
    #pragma unroll
    for (int ck = 0; ck < 2; ck++) {
      gload_lds16(srcA[ck] + kt * 32, &lA[(w * 64 + ck * 256) * 8]);
      gload_lds16(srcB[ck] + kt * 32, &lB[(w * 64 + ck * 256) * 8]);
    }
    __syncthreads();
    bf16x8 af[4], bfr[4];
    #pragma unroll
    for (int m = 0; m < 4; m++) af[m] = *(const bf16x8*)&lA[(ra + m * 16) * 32 + ko];
    #pragma unroll
    for (int n = 0; n < 4; n++) bfr[n] = *(const bf16x8*)&lB[(rb + n * 16) * 32 + ko];
    #pragma unroll
    for (int m = 0; m < 4; m++)
      #pragma unroll
      for (int n = 0; n < 4; n++)
        acc[m][n] = __builtin_amdgcn_mfma_f32_16x16x32_bf16(af[m], bfr[n], acc[m][n], 0, 0, 0);
  }

  int rowbase = j0 + wr * 64;
  int colbase = bn * 128 + wc * 64;
  #pragma unroll
  for (int m = 0; m < 4; m++) {
    #pragma unroll
    for (int n = 0; n < 4; n++) {
      #pragma unroll
      for (int v = 0; v < 4; v++) {
        int r = rowbase + m * 16 + (l >> 4) * 4 + v;
        int cc = colbase + n * 16 + (l & 15);
        if (r < jend) {
          if (MODE == 1) {
            outF[(size_t)kc * (NTOK * R_DIM) + (size_t)r * R_DIM + cc] = acc[m][n][v];
          } else {
            size_t o = (size_t)perm[r] * O_DIM + cc;
            outF[o] += 2.0f * acc[m][n][v];
          }
        }
      }
    }
  }
}

// ---------------- reduce split-K partials -> bf16 H16s ----------------
__global__ void reduce_h(const float* __restrict__ hp, unsigned short* __restrict__ h16) {
  size_t g = (size_t)blockIdx.x * 256 + threadIdx.x;   // one float4 position
  const float4* h4 = (const float4*)hp;
  float4 s = h4[g];
  #pragma unroll
  for (int c = 1; c < KSPLIT; c++) {
    float4 p = h4[g + (size_t)c * (NTOK * R_DIM / 4)];
    s.x += p.x; s.y += p.y; s.z += p.z; s.w += p.w;
  }
  union { unsigned short h[4]; uint2 v; } u;
  u.h[0] = f2bf(s.x); u.h[1] = f2bf(s.y); u.h[2] = f2bf(s.z); u.h[3] = f2bf(s.w);
  ((uint2*)h16)[g] = u.v;
}

// ---------------- workspace layout (bytes) ----------------
#define X16_OFF   ((size_t)0)             // 8192*4096*2   = 67108864
#define W16_OFF   ((size_t)67108864)      // 4096*4096*2   = 33554432 (reused as HP)
#define A16T_OFF  ((size_t)100663296)     // 8*256*4096*2  = 16777216  [E][R][D]
#define B16T_OFF  ((size_t)117440512)     // 8*4096*256*2  = 16777216  [E][O][R]
#define H16S_OFF  ((size_t)134217728)     // 8192*256*2    = 4194304
#define PERM_OFF  ((size_t)138412032)     // 8192*4
#define TILEE_OFF ((size_t)138444800)     // 96*4
#define TILEJ0_OFF ((size_t)138445184)
#define TILEJE_OFF ((size_t)138445568)
#define NT_OFF    ((size_t)138445952)

extern "C" void kernel_launch(void* const* d_in, const int* in_sizes, int n_in,
                              void* d_out, int out_size, void* d_ws, size_t ws_size,
                              hipStream_t stream) {
  const float* x  = (const float*)d_in[0];   // [2,4096,4096]
  const float* wb = (const float*)d_in[1];   // [4096,4096]
  const float* la = (const float*)d_in[2];   // [8,4096,256]
  const float* lb = (const float*)d_in[3];   // [8,256,4096]
  const int* tok  = (const int*)d_in[4];     // [4096]
  float* out = (float*)d_out;                // [2,4096,4096]

  char* ws = (char*)d_ws;
  unsigned short* X16  = (unsigned short*)(ws + X16_OFF);
  unsigned short* W16  = (unsigned short*)(ws + W16_OFF);
  unsigned short* A16t = (unsigned short*)(ws + A16T_OFF);
  unsigned short* B16t = (unsigned short*)(ws + B16T_OFF);
  unsigned short* H16s = (unsigned short*)(ws + H16S_OFF);
  float* HP = (float*)(ws + W16_OFF);        // reuse W16 space after dense GEMM
  int* perm  = (int*)(ws + PERM_OFF);
  int* tl_e  = (int*)(ws + TILEE_OFF);
  int* tl_j0 = (int*)(ws + TILEJ0_OFF);
  int* tl_je = (int*)(ws + TILEJE_OFF);
  int* nt    = (int*)(ws + NT_OFF);

  // casts
  cast8<<<16384, 256, 0, stream>>>(x, X16);
  cast8<<<8192, 256, 0, stream>>>(wb, W16);
  transpose_cast<<<dim3(128, 8, 8), 256, 0, stream>>>(la, A16t, D_DIM, R_DIM);
  transpose_cast<<<dim3(8, 128, 8), 256, 0, stream>>>(lb, B16t, R_DIM, O_DIM);
  sort_tokens<<<1, 256, 0, stream>>>(tok, perm, tl_e, tl_j0, tl_je, nt);

  // base GEMM: out = X @ W^T   (256^2 wave-drift pipelined kernel, K fixed)
  gemm256_dense<<<512, 512, 0, stream>>>(X16, W16, out);

  // LoRA stage 1 (split-K x4): HP[kc] = partial(X[perm] @ A_e^T)  — overwrites W16 space
  gemm_nt<1><<<dim3(71, 2, KSPLIT), 256, 0, stream>>>(X16, A16t, HP,
                                                      perm, tl_e, tl_j0, tl_je, nt, D_DIM);
  reduce_h<<<2048, 256, 0, stream>>>(HP, H16s);

  // LoRA stage 2: out[perm] += 2 * H_sorted @ B_e^T
  gemm_nt<2><<<dim3(71, 32), 256, 0, stream>>>(H16s, B16t, out,
                                               perm, tl_e, tl_j0, tl_je, nt, R_DIM);
}

// Round 8
// 459.997 us; speedup vs baseline: 1.3891x; 1.3891x over previous
//
#include <hip/hip_runtime.h>

// Problem constants
#define S_TOK 4096
#define D_DIM 4096
#define O_DIM 4096
#define R_DIM 256
#define E_EXP 8
#define NTOK  8192   // B*S
#define KSPLIT 4

typedef __bf16 bf16x8 __attribute__((ext_vector_type(8)));
typedef float  f32x4  __attribute__((ext_vector_type(4)));

__device__ __forceinline__ unsigned short f2bf(float f) {
  unsigned int u = __float_as_uint(f);
  u += 0x7FFFu + ((u >> 16) & 1u);   // RNE (no NaN in data)
  return (unsigned short)(u >> 16);
}
__device__ __forceinline__ float bf2f(unsigned short h) {
  return __uint_as_float(((unsigned int)h) << 16);
}

__device__ __forceinline__ void gload_lds16(const unsigned short* g, unsigned short* l) {
  __builtin_amdgcn_global_load_lds((const __attribute__((address_space(1))) void*)g,
                                   (__attribute__((address_space(3))) void*)l, 16, 0, 0);
}

// Fused counted-wait + barrier as ONE volatile asm with memory clobber.
#define PIPE_FENCE(N)                                                        \
  do {                                                                       \
    asm volatile("s_waitcnt vmcnt(" #N ")\n\ts_barrier" ::: "memory");       \
    __builtin_amdgcn_sched_barrier(0);                                       \
  } while (0)
#define LGKM0                                                                \
  do {                                                                       \
    asm volatile("s_waitcnt lgkmcnt(0)" ::: "memory");                       \
    __builtin_amdgcn_sched_barrier(0);                                       \
  } while (0)
#define SBAR0 __builtin_amdgcn_sched_barrier(0)

// ---------------- cast f32 -> bf16, 8 elems/thread ----------------
__global__ void cast8(const float* __restrict__ in, unsigned short* __restrict__ out) {
  size_t g = (size_t)blockIdx.x * 256 + threadIdx.x;
  const float4* i4 = (const float4*)in;
  float4 a = i4[g * 2], b = i4[g * 2 + 1];
  union { unsigned short h[8]; int4 v; } u;
  u.h[0] = f2bf(a.x); u.h[1] = f2bf(a.y); u.h[2] = f2bf(a.z); u.h[3] = f2bf(a.w);
  u.h[4] = f2bf(b.x); u.h[5] = f2bf(b.y); u.h[6] = f2bf(b.z); u.h[7] = f2bf(b.w);
  ((int4*)out)[g] = u.v;
}

// ------------- transpose+cast: in[e][P][Q] f32 -> out[e][Q][P] bf16 -------------
__global__ void transpose_cast(const float* __restrict__ in, unsigned short* __restrict__ out,
                               int P, int Q) {
  __shared__ unsigned short tile[32][33];
  int e = blockIdx.z;
  int pt = blockIdx.x * 32, qt = blockIdx.y * 32;
  const float* ie = in + (size_t)e * P * Q;
  unsigned short* oe = out + (size_t)e * P * Q;
  int tx = threadIdx.x & 31, ty = threadIdx.x >> 5;
  #pragma unroll
  for (int i = 0; i < 32; i += 8) {
    int p = pt + ty + i, q = qt + tx;
    tile[ty + i][tx] = f2bf(ie[(size_t)p * Q + q]);
  }
  __syncthreads();
  #pragma unroll
  for (int i = 0; i < 32; i += 8) {
    int q = qt + ty + i, p = pt + tx;
    oe[(size_t)q * P + p] = tile[tx][ty + i];
  }
}

// ------------- deterministic stable counting sort of tokens by expert -------------
__global__ void sort_tokens(const int* __restrict__ tt, int* __restrict__ token_perm,
                            int* __restrict__ inv_perm,
                            int* __restrict__ tile_e, int* __restrict__ tile_j0,
                            int* __restrict__ tile_jend, int* __restrict__ ntiles_out) {
  __shared__ int ltt[S_TOK];
  __shared__ int lc[256 * 8];
  __shared__ int basee[8], cnte[8];
  __shared__ int ssl[S_TOK];
  int t = threadIdx.x;
  for (int s = t; s < S_TOK; s += 256) ltt[s] = tt[s];
  __syncthreads();
  int c[8] = {0,0,0,0,0,0,0,0};
  #pragma unroll
  for (int i = 0; i < 16; i++) { int e = ltt[t * 16 + i]; c[e]++; }
  #pragma unroll
  for (int e = 0; e < 8; e++) lc[t * 8 + e] = c[e];
  __syncthreads();
  if (t < 8) {
    int run = 0;
    for (int q = 0; q < 256; q++) { int tmp = lc[q * 8 + t]; lc[q * 8 + t] = run; run += tmp; }
    cnte[t] = run;
  }
  __syncthreads();
  if (t == 0) { int tot = 0; for (int e = 0; e < 8; e++) { basee[e] = tot; tot += cnte[e]; } }
  __syncthreads();
  int off[8];
  #pragma unroll
  for (int e = 0; e < 8; e++) off[e] = basee[e] + lc[t * 8 + e];
  #pragma unroll
  for (int i = 0; i < 16; i++) { int s = t * 16 + i; int e = ltt[s]; ssl[off[e]++] = s; }
  __syncthreads();
  for (int j = t; j < NTOK; j += 256) {
    int row = ((j & 1) << 12) + ssl[j >> 1];
    token_perm[j] = row;
    inv_perm[row] = j;
  }
  if (t == 0) {
    int nt = 0;
    for (int e = 0; e < 8; e++) {
      int js = 2 * basee[e], je = js + 2 * cnte[e];
      for (int j0 = js; j0 < je; j0 += 128) {
        tile_e[nt] = e; tile_j0[nt] = j0;
        tile_jend[nt] = (je < j0 + 128) ? je : (j0 + 128);
        nt++;
      }
    }
    *ntiles_out = nt;
  }
}

// ===================== 256x256 read-ahead pipelined dense GEMM =====================
// C = A @ B^T (+ 2*lora via lout when FUSED). bf16 in, f32 out.
// 8 waves (2Mx4N), wave tile 128x64. BK=64 as two k-halves; NKT=64 tiles.
// LDS: [ring2][khalf2] 16KB slots per operand = 128 KiB.
// Phase p: {issue ds_reads for phase p+1} {stage 1 half} -> MFMA(p) on frags
// drained LAST phase -> lgkmcnt(0) -> fused vmcnt(6)+barrier.  MFMA overlaps the
// LDS drain of its own next-phase reads (R5 serialized these: 6019 cyc/K-tile).
// Stage map: ph0->A-k1(t+1), ph1->B-k1(t+1), ph2->A-k0(t+2), ph3->B-k0(t+2).
// vmcnt ledger (2 loads/stage): uniform vmcnt(6) protects reads issued one phase
// ahead of use (verified steady + prologue); tail fences 6,6,4,4 then 0,0.
template<int FUSED>
__global__ __launch_bounds__(512, 2) void gemm256_dense(
    const unsigned short* __restrict__ A, const unsigned short* __restrict__ B,
    float* __restrict__ C, const unsigned short* __restrict__ lout,
    const int* __restrict__ invp) {
  __shared__ __align__(16) unsigned short ldsA[2][2][8192];
  __shared__ __align__(16) unsigned short ldsB[2][2][8192];
  // 2D XCD swizzle: XCDs as 4x2 grid of 8bm x 8bn blocks (A-panel fill 544->~260MB)
  int b = blockIdx.x;
  int xc = b & 7, q = b >> 3;
  const int bm = (xc >> 1) * 8 + (q >> 3);   // 0..31
  const int bn = (xc & 1) * 8 + (q & 7);     // 0..15
  const int tid = threadIdx.x, l = tid & 63, w = tid >> 6;
  const int wm = w >> 2, wn = w & 3;

  // staging source pointers (inverse-swizzled global, linear LDS dest)
  const unsigned short *srcA0, *srcA1, *srcB0, *srcB1;
  {
    int i0 = tid, r0 = i0 >> 2;
    int c0 = ((i0 & 3) * 16) ^ (((r0 >> 1) & 3) << 4);
    srcA0 = A + (size_t)(bm * 256 + r0) * 4096 + (c0 >> 1);
    srcB0 = B + (size_t)(bn * 256 + r0) * 4096 + (c0 >> 1);
    int i1 = 512 + tid, r1 = i1 >> 2;
    int c1 = ((i1 & 3) * 16) ^ (((r1 >> 1) & 3) << 4);
    srcA1 = A + (size_t)(bm * 256 + r1) * 4096 + (c1 >> 1);
    srcB1 = B + (size_t)(bn * 256 + r1) * 4096 + (c1 >> 1);
  }
  const int d0 = tid * 8;

  // swizzled ds_read byte-offsets within one 16KB slot
  const int lane15 = l & 15, kb16 = (l >> 4) * 16;
  int offA[8], offB[4];
  #pragma unroll
  for (int m = 0; m < 8; m++) {
    int r = wm * 128 + m * 16 + lane15;
    offA[m] = r * 64 + (kb16 ^ (((r >> 1) & 3) << 4));
  }
  #pragma unroll
  for (int n = 0; n < 4; n++) {
    int r = wn * 64 + n * 16 + lane15;
    offB[n] = r * 64 + (kb16 ^ (((r >> 1) & 3) << 4));
  }

  f32x4 acc[8][4];
  #pragma unroll
  for (int m = 0; m < 8; m++)
    #pragma unroll
    for (int n = 0; n < 4; n++) acc[m][n] = (f32x4){0.f, 0.f, 0.f, 0.f};

  bf16x8 Ab0[4], Ab1[4], Bb0[4], Bb1[4];

#define STAGE_A(tt, kh) do { int _o = (tt) * 64 + (kh) * 32;                  \
    gload_lds16(srcA0 + _o, &ldsA[(tt) & 1][kh][d0]);                         \
    gload_lds16(srcA1 + _o, &ldsA[(tt) & 1][kh][d0 + 4096]); } while (0)
#define STAGE_B(tt, kh) do { int _o = (tt) * 64 + (kh) * 32;                  \
    gload_lds16(srcB0 + _o, &ldsB[(tt) & 1][kh][d0]);                         \
    gload_lds16(srcB1 + _o, &ldsB[(tt) & 1][kh][d0 + 4096]); } while (0)
#define RD_A(RING, QQ, KS, BUF) do {                                          \
    const char* _s = (const char*)&ldsA[RING][KS][0];                         \
    BUF[0] = *(const bf16x8*)(_s + offA[(QQ) * 4 + 0]);                       \
    BUF[1] = *(const bf16x8*)(_s + offA[(QQ) * 4 + 1]);                       \
    BUF[2] = *(const bf16x8*)(_s + offA[(QQ) * 4 + 2]);                       \
    BUF[3] = *(const bf16x8*)(_s + offA[(QQ) * 4 + 3]); } while (0)
#define RD_B(RING, KS, BUF) do {                                              \
    const char* _s = (const char*)&ldsB[RING][KS][0];                         \
    BUF[0] = *(const bf16x8*)(_s + offB[0]);                                  \
    BUF[1] = *(const bf16x8*)(_s + offB[1]);                                  \
    BUF[2] = *(const bf16x8*)(_s + offB[2]);                                  \
    BUF[3] = *(const bf16x8*)(_s + offB[3]); } while (0)
#define PRIO_MFMA(Q, AB, BB) do {                                             \
    __builtin_amdgcn_s_setprio(1);                                            \
    _Pragma("unroll")                                                         \
    for (int mm = 0; mm < 4; mm++)                                            \
      _Pragma("unroll")                                                       \
      for (int nn = 0; nn < 4; nn++)                                          \
        acc[(Q) * 4 + mm][nn] = __builtin_amdgcn_mfma_f32_16x16x32_bf16(      \
            AB[mm], BB[nn], acc[(Q) * 4 + mm][nn], 0, 0, 0);                  \
    __builtin_amdgcn_s_setprio(0); } while (0)

  // prologue: h1..h6 = A0k0,B0k0,A0k1,B0k1,A1k0,B1k0 (12 loads)
  STAGE_A(0, 0); STAGE_B(0, 0); STAGE_A(0, 1); STAGE_B(0, 1);
  STAGE_A(1, 0); STAGE_B(1, 0);
  PIPE_FENCE(8);                 // h1,h2 (A0k0,B0k0) landed
  RD_B(0, 0, Bb0); RD_A(0, 0, 0, Ab0);
  LGKM0;

  // steady: tiles 0..61
  #pragma unroll 1
  for (int t = 0; t < 62; ++t) {
    const int r = t & 1, nr = r ^ 1;
    // ph0: MFMA q0*k0 ; read A(q1,k0) ; stage A-k1(t+1)
    RD_A(r, 1, 0, Ab1); STAGE_A(t + 1, 1); SBAR0;
    PRIO_MFMA(0, Ab0, Bb0);
    LGKM0; PIPE_FENCE(6);
    // ph1: MFMA q1*k0 ; read B-k1, A(q0,k1) ; stage B-k1(t+1)
    RD_B(r, 1, Bb1); RD_A(r, 0, 1, Ab0); STAGE_B(t + 1, 1); SBAR0;
    PRIO_MFMA(1, Ab1, Bb0);
    LGKM0; PIPE_FENCE(6);
    // ph2: MFMA q0*k1 ; read A(q1,k1) ; stage A-k0(t+2)
    RD_A(r, 1, 1, Ab1); STAGE_A(t + 2, 0); SBAR0;
    PRIO_MFMA(0, Ab0, Bb1);
    LGKM0; PIPE_FENCE(6);
    // ph3: MFMA q1*k1 ; read B-k0(t+1), A(q0,k0)(t+1) ; stage B-k0(t+2)
    RD_B(nr, 0, Bb0); RD_A(nr, 0, 0, Ab0); STAGE_B(t + 2, 0); SBAR0;
    PRIO_MFMA(1, Ab1, Bb1);
    LGKM0; PIPE_FENCE(6);
  }
  // tile 62 (r=0): stages only k1(63); fences 6,6,4,4
  RD_A(0, 1, 0, Ab1); STAGE_A(63, 1); SBAR0; PRIO_MFMA(0, Ab0, Bb0); LGKM0; PIPE_FENCE(6);
  RD_B(0, 1, Bb1); RD_A(0, 0, 1, Ab0); STAGE_B(63, 1); SBAR0; PRIO_MFMA(1, Ab1, Bb0); LGKM0; PIPE_FENCE(6);
  RD_A(0, 1, 1, Ab1); SBAR0; PRIO_MFMA(0, Ab0, Bb1); LGKM0; PIPE_FENCE(4);
  RD_B(1, 0, Bb0); RD_A(1, 0, 0, Ab0); SBAR0; PRIO_MFMA(1, Ab1, Bb1); LGKM0; PIPE_FENCE(4);
  // tile 63 (r=1): drain 0
  RD_A(1, 1, 0, Ab1); SBAR0; PRIO_MFMA(0, Ab0, Bb0); LGKM0; PIPE_FENCE(0);
  RD_B(1, 1, Bb1); RD_A(1, 0, 1, Ab0); SBAR0; PRIO_MFMA(1, Ab1, Bb0); LGKM0; PIPE_FENCE(0);
  RD_A(1, 1, 1, Ab1); SBAR0; PRIO_MFMA(0, Ab0, Bb1); LGKM0;
  PRIO_MFMA(1, Ab1, Bb1);

#undef STAGE_A
#undef STAGE_B
#undef RD_A
#undef RD_B
#undef PRIO_MFMA

  const int rowbase = bm * 256 + wm * 128;
  const int colbase = bn * 256 + wn * 64;
  #pragma unroll
  for (int m = 0; m < 8; m++)
    #pragma unroll
    for (int v = 0; v < 4; v++) {
      int rrow = rowbase + m * 16 + (l >> 4) * 4 + v;
      float lv0 = 0.f, lv1 = 0.f, lv2 = 0.f, lv3 = 0.f;
      if (FUSED) {
        int jr = invp[rrow];
        const unsigned short* lr = lout + (size_t)jr * O_DIM + colbase + lane15;
        lv0 = bf2f(lr[0]); lv1 = bf2f(lr[16]); lv2 = bf2f(lr[32]); lv3 = bf2f(lr[48]);
      }
      size_t base = (size_t)rrow * O_DIM + colbase + lane15;
      C[base]      = acc[m][0][v] + lv0;
      C[base + 16] = acc[m][1][v] + lv1;
      C[base + 32] = acc[m][2][v] + lv2;
      C[base + 48] = acc[m][3][v] + lv3;
    }
}

// ------------- 128x128 skeleton for the LoRA GEMMs -------------
// MODE 1: outU[kc][j][r] = bf16 partial( X[perm[j]] @ A16t[e]^T ), K-chunk kc
// MODE 2: outF[perm[j]] += 2 * H16s @ B16t[e]^T   (RMW fallback)
// MODE 3: outU[j] = bf16( 2 * H16s @ B16t[e]^T )  (pure write, sorted rows)
template<int MODE>
__global__ __launch_bounds__(256, 2) void gemm_nt(
    const unsigned short* __restrict__ Aop, const unsigned short* __restrict__ Bop,
    float* __restrict__ outF, unsigned short* __restrict__ outU,
    const int* __restrict__ perm, const int* __restrict__ tile_e,
    const int* __restrict__ tile_j0, const int* __restrict__ tile_jend,
    const int* __restrict__ ntiles, int K) {
  int bm = blockIdx.x, bn = blockIdx.y;
  if (bm >= *ntiles) return;
  int e = tile_e[bm], j0 = tile_j0[bm], jend = tile_jend[bm];
  const int kc = (MODE == 1) ? blockIdx.z : 0;
  const int t = threadIdx.x;
  const int l = t & 63, w = t >> 6;
  __shared__ __align__(16) unsigned short lA[128 * 32];
  __shared__ __align__(16) unsigned short lB[128 * 32];

  const unsigned short* srcA[2];
  const unsigned short* srcB[2];
  #pragma unroll
  for (int ck = 0; ck < 2; ck++) {
    int idx = t + ck * 256;
    int lrow = idx >> 2, lk = (idx & 3) * 8;
    int j = j0 + lrow; if (j > jend - 1) j = jend - 1;
    int grow = (MODE == 1) ? perm[j] : j;
    srcA[ck] = Aop + (size_t)grow * K + lk + kc * 1024;
    int bcol = bn * 128 + lrow;
    const unsigned short* bp = Bop;
    if (MODE == 1) bp += (size_t)e * R_DIM * D_DIM;
    else           bp += (size_t)e * O_DIM * R_DIM;
    srcB[ck] = bp + (size_t)bcol * K + lk + kc * 1024;
  }

  f32x4 acc[4][4];
  #pragma unroll
  for (int m = 0; m < 4; m++)
    #pragma unroll
    for (int n = 0; n < 4; n++) acc[m][n] = (f32x4){0.f, 0.f, 0.f, 0.f};

  const int wr = w >> 1, wc = w & 1;
  const int ra = wr * 64 + (l & 15);
  const int rb = wc * 64 + (l & 15);
  const int ko = (l >> 4) * 8;

  const int nk = (MODE == 1) ? (1024 / 32) : (K / 32);
  for (int kt = 0; kt < nk; kt++) {
    __syncthreads();
    #pragma unroll
    for (int ck = 0; ck < 2; ck++) {
      gload_lds16(srcA[ck] + kt * 32, &lA[(w * 64 + ck * 256) * 8]);
      gload_lds16(srcB[ck] + kt * 32, &lB[(w * 64 + ck * 256) * 8]);
    }
    __syncthreads();
    bf16x8 af[4], bfr[4];
    #pragma unroll
    for (int m = 0; m < 4; m++) af[m] = *(const bf16x8*)&lA[(ra + m * 16) * 32 + ko];
    #pragma unroll
    for (int n = 0; n < 4; n++) bfr[n] = *(const bf16x8*)&lB[(rb + n * 16) * 32 + ko];
    #pragma unroll
    for (int m = 0; m < 4; m++)
      #pragma unroll
      for (int n = 0; n < 4; n++)
        acc[m][n] = __builtin_amdgcn_mfma_f32_16x16x32_bf16(af[m], bfr[n], acc[m][n], 0, 0, 0);
  }

  int rowbase = j0 + wr * 64;
  int colbase = bn * 128 + wc * 64;
  #pragma unroll
  for (int m = 0; m < 4; m++) {
    #pragma unroll
    for (int n = 0; n < 4; n++) {
      #pragma unroll
      for (int v = 0; v < 4; v++) {
        int r = rowbase + m * 16 + (l >> 4) * 4 + v;
        int cc = colbase + n * 16 + (l & 15);
        if (r < jend) {
          if (MODE == 1) {
            outU[(size_t)kc * (NTOK * R_DIM) + (size_t)r * R_DIM + cc] = f2bf(acc[m][n][v]);
          } else if (MODE == 2) {
            size_t o = (size_t)perm[r] * O_DIM + cc;
            outF[o] += 2.0f * acc[m][n][v];
          } else {
            outU[(size_t)r * O_DIM + cc] = f2bf(2.0f * acc[m][n][v]);
          }
        }
      }
    }
  }
}

// ---------------- reduce bf16 split-K partials -> bf16 H16s ----------------
__global__ void reduce_h(const unsigned short* __restrict__ hp, unsigned short* __restrict__ h16) {
  size_t g = (size_t)blockIdx.x * 256 + threadIdx.x;   // 8-elem group
  float s[8] = {0,0,0,0,0,0,0,0};
  #pragma unroll
  for (int c = 0; c < KSPLIT; c++) {
    int4 v = ((const int4*)hp)[g + (size_t)c * (NTOK * R_DIM / 8)];
    const unsigned short* us = (const unsigned short*)&v;
    #pragma unroll
    for (int i = 0; i < 8; i++) s[i] += bf2f(us[i]);
  }
  union { unsigned short h[8]; int4 v; } u;
  #pragma unroll
  for (int i = 0; i < 8; i++) u.h[i] = f2bf(s[i]);
  ((int4*)h16)[g] = u.v;
}

// ---------------- workspace layout (bytes) ----------------
#define X16_OFF   ((size_t)0)             // 67108864
#define W16_OFF   ((size_t)67108864)      // 33554432 (fallback: reused as HP16)
#define A16T_OFF  ((size_t)100663296)     // 16777216
#define B16T_OFF  ((size_t)117440512)     // 16777216
#define H16S_OFF  ((size_t)134217728)     // 4194304
#define PERM_OFF  ((size_t)138412032)     // 32768
#define INVP_OFF  ((size_t)138444800)     // 32768
#define TILEE_OFF ((size_t)138477568)     // 512
#define TILEJ0_OFF ((size_t)138478080)
#define TILEJE_OFF ((size_t)138478592)
#define NT_OFF    ((size_t)138479104)
#define HP16_OFF  ((size_t)138479616)     // 16777216 (fused flow)
#define LOUT_OFF  ((size_t)155256832)     // 67108864
#define WS_FUSED_NEED ((size_t)222365696)

extern "C" void kernel_launch(void* const* d_in, const int* in_sizes, int n_in,
                              void* d_out, int out_size, void* d_ws, size_t ws_size,
                              hipStream_t stream) {
  const float* x  = (const float*)d_in[0];
  const float* wb = (const float*)d_in[1];
  const float* la = (const float*)d_in[2];
  const float* lb = (const float*)d_in[3];
  const int* tok  = (const int*)d_in[4];
  float* out = (float*)d_out;

  char* ws = (char*)d_ws;
  unsigned short* X16  = (unsigned short*)(ws + X16_OFF);
  unsigned short* W16  = (unsigned short*)(ws + W16_OFF);
  unsigned short* A16t = (unsigned short*)(ws + A16T_OFF);
  unsigned short* B16t = (unsigned short*)(ws + B16T_OFF);
  unsigned short* H16s = (unsigned short*)(ws + H16S_OFF);
  int* perm  = (int*)(ws + PERM_OFF);
  int* invp  = (int*)(ws + INVP_OFF);
  int* tl_e  = (int*)(ws + TILEE_OFF);
  int* tl_j0 = (int*)(ws + TILEJ0_OFF);
  int* tl_je = (int*)(ws + TILEJE_OFF);
  int* nt    = (int*)(ws + NT_OFF);

  const bool fused = ws_size >= WS_FUSED_NEED;

  cast8<<<16384, 256, 0, stream>>>(x, X16);
  cast8<<<8192, 256, 0, stream>>>(wb, W16);
  transpose_cast<<<dim3(128, 8, 8), 256, 0, stream>>>(la, A16t, D_DIM, R_DIM);
  transpose_cast<<<dim3(8, 128, 8), 256, 0, stream>>>(lb, B16t, R_DIM, O_DIM);
  sort_tokens<<<1, 256, 0, stream>>>(tok, perm, invp, tl_e, tl_j0, tl_je, nt);

  if (fused) {
    unsigned short* HP16 = (unsigned short*)(ws + HP16_OFF);
    unsigned short* LOUT = (unsigned short*)(ws + LOUT_OFF);
    // LoRA: H partials -> H16s -> lout (pure write, sorted rows), then dense+add
    gemm_nt<1><<<dim3(71, 2, KSPLIT), 256, 0, stream>>>(X16, A16t, nullptr, HP16,
                                                        perm, tl_e, tl_j0, tl_je, nt, D_DIM);
    reduce_h<<<1024, 256, 0, stream>>>(HP16, H16s);
    gemm_nt<3><<<dim3(71, 32), 256, 0, stream>>>(H16s, B16t, nullptr, LOUT,
                                                 perm, tl_e, tl_j0, tl_je, nt, R_DIM);
    gemm256_dense<1><<<512, 512, 0, stream>>>(X16, W16, out, LOUT, invp);
  } else {
    unsigned short* HP16 = (unsigned short*)(ws + W16_OFF);  // dense done, reuse
    gemm256_dense<0><<<512, 512, 0, stream>>>(X16, W16, out, nullptr, nullptr);
    gemm_nt<1><<<dim3(71, 2, KSPLIT), 256, 0, stream>>>(X16, A16t, nullptr, HP16,
                                                        perm, tl_e, tl_j0, tl_je, nt, D_DIM);
    reduce_h<<<1024, 256, 0, stream>>>(HP16, H16s);
    gemm_nt<2><<<dim3(71, 32), 256, 0, stream>>>(H16s, B16t, out, nullptr,
                                                 perm, tl_e, tl_j0, tl_je, nt, R_DIM);
  }
}

// Round 9
// 456.869 us; speedup vs baseline: 1.3986x; 1.0068x over previous
//
#include <hip/hip_runtime.h>

// Problem constants
#define S_TOK 4096
#define D_DIM 4096
#define O_DIM 4096
#define R_DIM 256
#define E_EXP 8
#define NTOK  8192   // B*S
#define KSPLIT 4

typedef __bf16 bf16x8 __attribute__((ext_vector_type(8)));
typedef float  f32x4  __attribute__((ext_vector_type(4)));

__device__ __forceinline__ unsigned short f2bf(float f) {
  unsigned int u = __float_as_uint(f);
  u += 0x7FFFu + ((u >> 16) & 1u);   // RNE (no NaN in data)
  return (unsigned short)(u >> 16);
}
__device__ __forceinline__ float bf2f(unsigned short h) {
  return __uint_as_float(((unsigned int)h) << 16);
}

__device__ __forceinline__ void gload_lds16(const unsigned short* g, unsigned short* l) {
  __builtin_amdgcn_global_load_lds((const __attribute__((address_space(1))) void*)g,
                                   (__attribute__((address_space(3))) void*)l, 16, 0, 0);
}

// Fused counted-wait + barrier as ONE volatile asm with memory clobber.
#define PIPE_FENCE(N)                                                        \
  do {                                                                       \
    asm volatile("s_waitcnt vmcnt(" #N ")\n\ts_barrier" ::: "memory");       \
    __builtin_amdgcn_sched_barrier(0);                                       \
  } while (0)
// Counted LDS wait: guarantees all reads OLDER than the newest N are done.
#define LGKMC(N)                                                             \
  do {                                                                       \
    asm volatile("s_waitcnt lgkmcnt(" #N ")" ::: "memory");                  \
    __builtin_amdgcn_sched_barrier(0);                                       \
  } while (0)
#define SBAR0 __builtin_amdgcn_sched_barrier(0)

// ---------------- cast f32 -> bf16, 8 elems/thread ----------------
__global__ void cast8(const float* __restrict__ in, unsigned short* __restrict__ out) {
  size_t g = (size_t)blockIdx.x * 256 + threadIdx.x;
  const float4* i4 = (const float4*)in;
  float4 a = i4[g * 2], b = i4[g * 2 + 1];
  union { unsigned short h[8]; int4 v; } u;
  u.h[0] = f2bf(a.x); u.h[1] = f2bf(a.y); u.h[2] = f2bf(a.z); u.h[3] = f2bf(a.w);
  u.h[4] = f2bf(b.x); u.h[5] = f2bf(b.y); u.h[6] = f2bf(b.z); u.h[7] = f2bf(b.w);
  ((int4*)out)[g] = u.v;
}

// ------------- transpose+cast: in[e][P][Q] f32 -> out[e][Q][P] bf16 -------------
__global__ void transpose_cast(const float* __restrict__ in, unsigned short* __restrict__ out,
                               int P, int Q) {
  __shared__ unsigned short tile[32][33];
  int e = blockIdx.z;
  int pt = blockIdx.x * 32, qt = blockIdx.y * 32;
  const float* ie = in + (size_t)e * P * Q;
  unsigned short* oe = out + (size_t)e * P * Q;
  int tx = threadIdx.x & 31, ty = threadIdx.x >> 5;
  #pragma unroll
  for (int i = 0; i < 32; i += 8) {
    int p = pt + ty + i, q = qt + tx;
    tile[ty + i][tx] = f2bf(ie[(size_t)p * Q + q]);
  }
  __syncthreads();
  #pragma unroll
  for (int i = 0; i < 32; i += 8) {
    int q = qt + ty + i, p = pt + tx;
    oe[(size_t)q * P + p] = tile[tx][ty + i];
  }
}

// ------------- deterministic stable counting sort of tokens by expert -------------
__global__ void sort_tokens(const int* __restrict__ tt, int* __restrict__ token_perm,
                            int* __restrict__ inv_perm,
                            int* __restrict__ tile_e, int* __restrict__ tile_j0,
                            int* __restrict__ tile_jend, int* __restrict__ ntiles_out) {
  __shared__ int ltt[S_TOK];
  __shared__ int lc[256 * 8];
  __shared__ int basee[8], cnte[8];
  __shared__ int ssl[S_TOK];
  int t = threadIdx.x;
  for (int s = t; s < S_TOK; s += 256) ltt[s] = tt[s];
  __syncthreads();
  int c[8] = {0,0,0,0,0,0,0,0};
  #pragma unroll
  for (int i = 0; i < 16; i++) { int e = ltt[t * 16 + i]; c[e]++; }
  #pragma unroll
  for (int e = 0; e < 8; e++) lc[t * 8 + e] = c[e];
  __syncthreads();
  if (t < 8) {
    int run = 0;
    for (int q = 0; q < 256; q++) { int tmp = lc[q * 8 + t]; lc[q * 8 + t] = run; run += tmp; }
    cnte[t] = run;
  }
  __syncthreads();
  if (t == 0) { int tot = 0; for (int e = 0; e < 8; e++) { basee[e] = tot; tot += cnte[e]; } }
  __syncthreads();
  int off[8];
  #pragma unroll
  for (int e = 0; e < 8; e++) off[e] = basee[e] + lc[t * 8 + e];
  #pragma unroll
  for (int i = 0; i < 16; i++) { int s = t * 16 + i; int e = ltt[s]; ssl[off[e]++] = s; }
  __syncthreads();
  for (int j = t; j < NTOK; j += 256) {
    int row = ((j & 1) << 12) + ssl[j >> 1];
    token_perm[j] = row;
    inv_perm[row] = j;
  }
  if (t == 0) {
    int nt = 0;
    for (int e = 0; e < 8; e++) {
      int js = 2 * basee[e], je = js + 2 * cnte[e];
      for (int j0 = js; j0 < je; j0 += 128) {
        tile_e[nt] = e; tile_j0[nt] = j0;
        tile_jend[nt] = (je < j0 + 128) ? je : (j0 + 128);
        nt++;
      }
    }
    *ntiles_out = nt;
  }
}

// ===================== 256x256 read-ahead dense GEMM (2 fences/K-tile) =============
// C = A @ B^T (+ 2*lora via lout when FUSED). bf16 in, f32 out.
// 8 waves (2Mx4N), wave tile 128x64. BK=64 as 2 k-halves; NKT=64 tiles.
// LDS: [ring2][khalf2] 16KB slots per operand = 128 KiB.
// Phase p: {RD for MFMA(p+1)} {stage 1 half} -> lgkmcnt(N=reads just issued)
// (prev phase's reads done; this phase's drain under MFMA) -> MFMA(p).
// Fences ONLY at ph1/ph3 ends: vmcnt(4)+barrier (R8 fenced every phase + full
// lgkm drain per phase -> ~1000 extra cyc/K-tile).
// Ledger: stage order A-k1(t+1)@ph0, B-k1(t+1)@ph1, A-k0(t+2)@ph2, B-k0(t+2)@ph3;
// F1(t)=vmcnt(4) lands A-k0(t+1),B-k0(t+1) (needed by ph3(t) reads);
// F3(t)=vmcnt(4) lands A-k1(t+1),B-k1(t+1) (needed by ph1(t+1) reads).
// WAR safety: every slot's last reader passes its counted-lgkm before the
// separating F-barrier; writers issue after it. Tail: F3(62)=0; tile 63 unfenced.
template<int FUSED>
__global__ __launch_bounds__(512, 2) void gemm256_dense(
    const unsigned short* __restrict__ A, const unsigned short* __restrict__ B,
    float* __restrict__ C, const unsigned short* __restrict__ lout,
    const int* __restrict__ invp) {
  __shared__ __align__(16) unsigned short ldsA[2][2][8192];
  __shared__ __align__(16) unsigned short ldsB[2][2][8192];
  // 2D XCD swizzle: XCDs as 4x2 grid of 8bm x 8bn blocks
  int b = blockIdx.x;
  int xc = b & 7, q = b >> 3;
  const int bm = (xc >> 1) * 8 + (q >> 3);   // 0..31
  const int bn = (xc & 1) * 8 + (q & 7);     // 0..15
  const int tid = threadIdx.x, l = tid & 63, w = tid >> 6;
  const int wm = w >> 2, wn = w & 3;

  // staging source pointers (inverse-swizzled global, linear LDS dest)
  const unsigned short *srcA0, *srcA1, *srcB0, *srcB1;
  {
    int i0 = tid, r0 = i0 >> 2;
    int c0 = ((i0 & 3) * 16) ^ (((r0 >> 1) & 3) << 4);
    srcA0 = A + (size_t)(bm * 256 + r0) * 4096 + (c0 >> 1);
    srcB0 = B + (size_t)(bn * 256 + r0) * 4096 + (c0 >> 1);
    int i1 = 512 + tid, r1 = i1 >> 2;
    int c1 = ((i1 & 3) * 16) ^ (((r1 >> 1) & 3) << 4);
    srcA1 = A + (size_t)(bm * 256 + r1) * 4096 + (c1 >> 1);
    srcB1 = B + (size_t)(bn * 256 + r1) * 4096 + (c1 >> 1);
  }
  const int d0 = tid * 8;

  // swizzled ds_read byte-offsets within one 16KB slot
  const int lane15 = l & 15, kb16 = (l >> 4) * 16;
  int offA[8], offB[4];
  #pragma unroll
  for (int m = 0; m < 8; m++) {
    int r = wm * 128 + m * 16 + lane15;
    offA[m] = r * 64 + (kb16 ^ (((r >> 1) & 3) << 4));
  }
  #pragma unroll
  for (int n = 0; n < 4; n++) {
    int r = wn * 64 + n * 16 + lane15;
    offB[n] = r * 64 + (kb16 ^ (((r >> 1) & 3) << 4));
  }

  f32x4 acc[8][4];
  #pragma unroll
  for (int m = 0; m < 8; m++)
    #pragma unroll
    for (int n = 0; n < 4; n++) acc[m][n] = (f32x4){0.f, 0.f, 0.f, 0.f};

  bf16x8 Ab0[4], Ab1[4], Bb0[4], Bb1[4];

#define STAGE_A(tt, kh) do { int _o = (tt) * 64 + (kh) * 32;                  \
    gload_lds16(srcA0 + _o, &ldsA[(tt) & 1][kh][d0]);                         \
    gload_lds16(srcA1 + _o, &ldsA[(tt) & 1][kh][d0 + 4096]); } while (0)
#define STAGE_B(tt, kh) do { int _o = (tt) * 64 + (kh) * 32;                  \
    gload_lds16(srcB0 + _o, &ldsB[(tt) & 1][kh][d0]);                         \
    gload_lds16(srcB1 + _o, &ldsB[(tt) & 1][kh][d0 + 4096]); } while (0)
#define RD_A(RING, QQ, KS, BUF) do {                                          \
    const char* _s = (const char*)&ldsA[RING][KS][0];                         \
    BUF[0] = *(const bf16x8*)(_s + offA[(QQ) * 4 + 0]);                       \
    BUF[1] = *(const bf16x8*)(_s + offA[(QQ) * 4 + 1]);                       \
    BUF[2] = *(const bf16x8*)(_s + offA[(QQ) * 4 + 2]);                       \
    BUF[3] = *(const bf16x8*)(_s + offA[(QQ) * 4 + 3]); } while (0)
#define RD_B(RING, KS, BUF) do {                                              \
    const char* _s = (const char*)&ldsB[RING][KS][0];                         \
    BUF[0] = *(const bf16x8*)(_s + offB[0]);                                  \
    BUF[1] = *(const bf16x8*)(_s + offB[1]);                                  \
    BUF[2] = *(const bf16x8*)(_s + offB[2]);                                  \
    BUF[3] = *(const bf16x8*)(_s + offB[3]); } while (0)
#define PRIO_MFMA(Q, AB, BB) do {                                             \
    __builtin_amdgcn_s_setprio(1);                                            \
    _Pragma("unroll")                                                         \
    for (int mm = 0; mm < 4; mm++)                                            \
      _Pragma("unroll")                                                       \
      for (int nn = 0; nn < 4; nn++)                                          \
        acc[(Q) * 4 + mm][nn] = __builtin_amdgcn_mfma_f32_16x16x32_bf16(      \
            AB[mm], BB[nn], acc[(Q) * 4 + mm][nn], 0, 0, 0);                  \
    __builtin_amdgcn_s_setprio(0); } while (0)

  // prologue: A0k0,B0k0,A0k1,B0k1,A1k0,B1k0 (12 loads); vmcnt(4) -> oldest 8 landed
  STAGE_A(0, 0); STAGE_B(0, 0); STAGE_A(0, 1); STAGE_B(0, 1);
  STAGE_A(1, 0); STAGE_B(1, 0);
  PIPE_FENCE(4);
  RD_B(0, 0, Bb0); RD_A(0, 0, 0, Ab0);   // 8 reads for MFMA(ph0(0))
  SBAR0;

  // steady: tiles 0..61
  #pragma unroll 1
  for (int t = 0; t < 62; ++t) {
    const int r = t & 1, nr = r ^ 1;
    // ph0: RD q1k0 (4) | stage A-k1(t+1) | lgkm(4): prev-phase reads done | MFMA q0k0
    RD_A(r, 1, 0, Ab1); SBAR0; STAGE_A(t + 1, 1); SBAR0; LGKMC(4);
    PRIO_MFMA(0, Ab0, Bb0);
    // ph1: RD Bk1 + q0k1 (8) | stage B-k1(t+1) | lgkm(8) | MFMA q1k0 | F1
    RD_B(r, 1, Bb1); RD_A(r, 0, 1, Ab0); SBAR0; STAGE_B(t + 1, 1); SBAR0; LGKMC(8);
    PRIO_MFMA(1, Ab1, Bb0);
    PIPE_FENCE(4);
    // ph2: RD q1k1 (4) | stage A-k0(t+2) | lgkm(4) | MFMA q0k1
    RD_A(r, 1, 1, Ab1); SBAR0; STAGE_A(t + 2, 0); SBAR0; LGKMC(4);
    PRIO_MFMA(0, Ab0, Bb1);
    // ph3: RD next-tile Bk0 + q0k0 (8) | stage B-k0(t+2) | lgkm(8) | MFMA q1k1 | F3
    RD_B(nr, 0, Bb0); RD_A(nr, 0, 0, Ab0); SBAR0; STAGE_B(t + 2, 0); SBAR0; LGKMC(8);
    PRIO_MFMA(1, Ab1, Bb1);
    PIPE_FENCE(4);
  }
  // tile 62 (r=0,nr=1): stages only k1(63); F3 drains to 0
  RD_A(0, 1, 0, Ab1); SBAR0; STAGE_A(63, 1); SBAR0; LGKMC(4); PRIO_MFMA(0, Ab0, Bb0);
  RD_B(0, 1, Bb1); RD_A(0, 0, 1, Ab0); SBAR0; STAGE_B(63, 1); SBAR0; LGKMC(8);
  PRIO_MFMA(1, Ab1, Bb0); PIPE_FENCE(4);
  RD_A(0, 1, 1, Ab1); SBAR0; LGKMC(4); PRIO_MFMA(0, Ab0, Bb1);
  RD_B(1, 0, Bb0); RD_A(1, 0, 0, Ab0); SBAR0; LGKMC(8); PRIO_MFMA(1, Ab1, Bb1);
  PIPE_FENCE(0);
  // tile 63 (r=1): no stages, no fences
  RD_A(1, 1, 0, Ab1); SBAR0; LGKMC(4); PRIO_MFMA(0, Ab0, Bb0);
  RD_B(1, 1, Bb1); RD_A(1, 0, 1, Ab0); SBAR0; LGKMC(8); PRIO_MFMA(1, Ab1, Bb0);
  RD_A(1, 1, 1, Ab1); SBAR0; LGKMC(4); PRIO_MFMA(0, Ab0, Bb1);
  LGKMC(0); PRIO_MFMA(1, Ab1, Bb1);

#undef STAGE_A
#undef STAGE_B
#undef RD_A
#undef RD_B
#undef PRIO_MFMA

  const int rowbase = bm * 256 + wm * 128;
  const int colbase = bn * 256 + wn * 64;
  #pragma unroll
  for (int m = 0; m < 8; m++)
    #pragma unroll
    for (int v = 0; v < 4; v++) {
      int rrow = rowbase + m * 16 + (l >> 4) * 4 + v;
      float lv0 = 0.f, lv1 = 0.f, lv2 = 0.f, lv3 = 0.f;
      if (FUSED) {
        int jr = invp[rrow];
        const unsigned short* lr = lout + (size_t)jr * O_DIM + colbase + lane15;
        lv0 = bf2f(lr[0]); lv1 = bf2f(lr[16]); lv2 = bf2f(lr[32]); lv3 = bf2f(lr[48]);
      }
      size_t base = (size_t)rrow * O_DIM + colbase + lane15;
      C[base]      = acc[m][0][v] + lv0;
      C[base + 16] = acc[m][1][v] + lv1;
      C[base + 32] = acc[m][2][v] + lv2;
      C[base + 48] = acc[m][3][v] + lv3;
    }
}

// ------------- 128x128 skeleton for the LoRA GEMMs -------------
// MODE 1: outU[kc][j][r] = bf16 partial( X[perm[j]] @ A16t[e]^T ), K-chunk kc
// MODE 2: outF[perm[j]] += 2 * H16s @ B16t[e]^T   (RMW fallback)
// MODE 3: outU[j] = bf16( 2 * H16s @ B16t[e]^T )  (pure write, sorted rows)
template<int MODE>
__global__ __launch_bounds__(256, 2) void gemm_nt(
    const unsigned short* __restrict__ Aop, const unsigned short* __restrict__ Bop,
    float* __restrict__ outF, unsigned short* __restrict__ outU,
    const int* __restrict__ perm, const int* __restrict__ tile_e,
    const int* __restrict__ tile_j0, const int* __restrict__ tile_jend,
    const int* __restrict__ ntiles, int K) {
  int bm = blockIdx.x, bn = blockIdx.y;
  if (bm >= *ntiles) return;
  int e = tile_e[bm], j0 = tile_j0[bm], jend = tile_jend[bm];
  const int kc = (MODE == 1) ? blockIdx.z : 0;
  const int t = threadIdx.x;
  const int l = t & 63, w = t >> 6;
  __shared__ __align__(16) unsigned short lA[128 * 32];
  __shared__ __align__(16) unsigned short lB[128 * 32];

  const unsigned short* srcA[2];
  const unsigned short* srcB[2];
  #pragma unroll
  for (int ck = 0; ck < 2; ck++) {
    int idx = t + ck * 256;
    int lrow = idx >> 2, lk = (idx & 3) * 8;
    int j = j0 + lrow; if (j > jend - 1) j = jend - 1;
    int grow = (MODE == 1) ? perm[j] : j;
    srcA[ck] = Aop + (size_t)grow * K + lk + kc * 1024;
    int bcol = bn * 128 + lrow;
    const unsigned short* bp = Bop;
    if (MODE == 1) bp += (size_t)e * R_DIM * D_DIM;
    else           bp += (size_t)e * O_DIM * R_DIM;
    srcB[ck] = bp + (size_t)bcol * K + lk + kc * 1024;
  }

  f32x4 acc[4][4];
  #pragma unroll
  for (int m = 0; m < 4; m++)
    #pragma unroll
    for (int n = 0; n < 4; n++) acc[m][n] = (f32x4){0.f, 0.f, 0.f, 0.f};

  const int wr = w >> 1, wc = w & 1;
  const int ra = wr * 64 + (l & 15);
  const int rb = wc * 64 + (l & 15);
  const int ko = (l >> 4) * 8;

  const int nk = (MODE == 1) ? (1024 / 32) : (K / 32);
  for (int kt = 0; kt < nk; kt++) {
    __syncthreads();
    #pragma unroll
    for (int ck = 0; ck < 2; ck++) {
      gload_lds16(srcA[ck] + kt * 32, &lA[(w * 64 + ck * 256) * 8]);
      gload_lds16(srcB[ck] + kt * 32, &lB[(w * 64 + ck * 256) * 8]);
    }
    __syncthreads();
    bf16x8 af[4], bfr[4];
    #pragma unroll
    for (int m = 0; m < 4; m++) af[m] = *(const bf16x8*)&lA[(ra + m * 16) * 32 + ko];
    #pragma unroll
    for (int n = 0; n < 4; n++) bfr[n] = *(const bf16x8*)&lB[(rb + n * 16) * 32 + ko];
    #pragma unroll
    for (int m = 0; m < 4; m++)
      #pragma unroll
      for (int n = 0; n < 4; n++)
        acc[m][n] = __builtin_amdgcn_mfma_f32_16x16x32_bf16(af[m], bfr[n], acc[m][n], 0, 0, 0);
  }

  int rowbase = j0 + wr * 64;
  int colbase = bn * 128 + wc * 64;
  #pragma unroll
  for (int m = 0; m < 4; m++) {
    #pragma unroll
    for (int n = 0; n < 4; n++) {
      #pragma unroll
      for (int v = 0; v < 4; v++) {
        int r = rowbase + m * 16 + (l >> 4) * 4 + v;
        int cc = colbase + n * 16 + (l & 15);
        if (r < jend) {
          if (MODE == 1) {
            outU[(size_t)kc * (NTOK * R_DIM) + (size_t)r * R_DIM + cc] = f2bf(acc[m][n][v]);
          } else if (MODE == 2) {
            size_t o = (size_t)perm[r] * O_DIM + cc;
            outF[o] += 2.0f * acc[m][n][v];
          } else {
            outU[(size_t)r * O_DIM + cc] = f2bf(2.0f * acc[m][n][v]);
          }
        }
      }
    }
  }
}

// ---------------- reduce bf16 split-K partials -> bf16 H16s ----------------
__global__ void reduce_h(const unsigned short* __restrict__ hp, unsigned short* __restrict__ h16) {
  size_t g = (size_t)blockIdx.x * 256 + threadIdx.x;   // 8-elem group
  float s[8] = {0,0,0,0,0,0,0,0};
  #pragma unroll
  for (int c = 0; c < KSPLIT; c++) {
    int4 v = ((const int4*)hp)[g + (size_t)c * (NTOK * R_DIM / 8)];
    const unsigned short* us = (const unsigned short*)&v;
    #pragma unroll
    for (int i = 0; i < 8; i++) s[i] += bf2f(us[i]);
  }
  union { unsigned short h[8]; int4 v; } u;
  #pragma unroll
  for (int i = 0; i < 8; i++) u.h[i] = f2bf(s[i]);
  ((int4*)h16)[g] = u.v;
}

// ---------------- workspace layout (bytes) ----------------
#define X16_OFF   ((size_t)0)             // 67108864
#define W16_OFF   ((size_t)67108864)      // 33554432 (fallback: reused as HP16)
#define A16T_OFF  ((size_t)100663296)     // 16777216
#define B16T_OFF  ((size_t)117440512)     // 16777216
#define H16S_OFF  ((size_t)134217728)     // 4194304
#define PERM_OFF  ((size_t)138412032)     // 32768
#define INVP_OFF  ((size_t)138444800)     // 32768
#define TILEE_OFF ((size_t)138477568)     // 512
#define TILEJ0_OFF ((size_t)138478080)
#define TILEJE_OFF ((size_t)138478592)
#define NT_OFF    ((size_t)138479104)
#define HP16_OFF  ((size_t)138479616)     // 16777216 (fused flow)
#define LOUT_OFF  ((size_t)155256832)     // 67108864
#define WS_FUSED_NEED ((size_t)222365696)

extern "C" void kernel_launch(void* const* d_in, const int* in_sizes, int n_in,
                              void* d_out, int out_size, void* d_ws, size_t ws_size,
                              hipStream_t stream) {
  const float* x  = (const float*)d_in[0];
  const float* wb = (const float*)d_in[1];
  const float* la = (const float*)d_in[2];
  const float* lb = (const float*)d_in[3];
  const int* tok  = (const int*)d_in[4];
  float* out = (float*)d_out;

  char* ws = (char*)d_ws;
  unsigned short* X16  = (unsigned short*)(ws + X16_OFF);
  unsigned short* W16  = (unsigned short*)(ws + W16_OFF);
  unsigned short* A16t = (unsigned short*)(ws + A16T_OFF);
  unsigned short* B16t = (unsigned short*)(ws + B16T_OFF);
  unsigned short* H16s = (unsigned short*)(ws + H16S_OFF);
  int* perm  = (int*)(ws + PERM_OFF);
  int* invp  = (int*)(ws + INVP_OFF);
  int* tl_e  = (int*)(ws + TILEE_OFF);
  int* tl_j0 = (int*)(ws + TILEJ0_OFF);
  int* tl_je = (int*)(ws + TILEJE_OFF);
  int* nt    = (int*)(ws + NT_OFF);

  const bool fused = ws_size >= WS_FUSED_NEED;

  cast8<<<16384, 256, 0, stream>>>(x, X16);
  cast8<<<8192, 256, 0, stream>>>(wb, W16);
  transpose_cast<<<dim3(128, 8, 8), 256, 0, stream>>>(la, A16t, D_DIM, R_DIM);
  transpose_cast<<<dim3(8, 128, 8), 256, 0, stream>>>(lb, B16t, R_DIM, O_DIM);
  sort_tokens<<<1, 256, 0, stream>>>(tok, perm, invp, tl_e, tl_j0, tl_je, nt);

  if (fused) {
    unsigned short* HP16 = (unsigned short*)(ws + HP16_OFF);
    unsigned short* LOUT = (unsigned short*)(ws + LOUT_OFF);
    gemm_nt<1><<<dim3(71, 2, KSPLIT), 256, 0, stream>>>(X16, A16t, nullptr, HP16,
                                                        perm, tl_e, tl_j0, tl_je, nt, D_DIM);
    reduce_h<<<1024, 256, 0, stream>>>(HP16, H16s);
    gemm_nt<3><<<dim3(71, 32), 256, 0, stream>>>(H16s, B16t, nullptr, LOUT,
                                                 perm, tl_e, tl_j0, tl_je, nt, R_DIM);
    gemm256_dense<1><<<512, 512, 0, stream>>>(X16, W16, out, LOUT, invp);
  } else {
    unsigned short* HP16 = (unsigned short*)(ws + W16_OFF);  // dense done, reuse
    gemm256_dense<0><<<512, 512, 0, stream>>>(X16, W16, out, nullptr, nullptr);
    gemm_nt<1><<<dim3(71, 2, KSPLIT), 256, 0, stream>>>(X16, A16t, nullptr, HP16,
                                                        perm, tl_e, tl_j0, tl_je, nt, D_DIM);
    reduce_h<<<1024, 256, 0, stream>>>(HP16, H16s);
    gemm_nt<2><<<dim3(71, 32), 256, 0, stream>>>(H16s, B16t, out, nullptr,
                                                 perm, tl_e, tl_j0, tl_je, nt, R_DIM);
  }
}